// Round 16
// baseline (281.502 us; speedup 1.0000x reference)
//
#include <hip/hip_runtime.h>
#include <hip/hip_bf16.h>

using u16 = unsigned short;
typedef float f32x4 __attribute__((ext_vector_type(4)));
typedef __bf16 bf16x8 __attribute__((ext_vector_type(8)));

#define T_SEQ 2048
#define C_DIM 2048
#define QKV_DIM 3072
#define N_HEAD 32
#define N_GROUPS 8
#define HEAD_SIZE 64
#define ROPE_N 16
#define NEG_BIG (-1e30f)
#define LSP 76    // lds_p row stride: 38 dwords/row -> quad offsets {0,24,16,8}, conflict-free
#define QSCALE 0.18033688011112043f   // 0.125 * log2(e): folds softmax's exp->exp2 conversion into Q

__device__ inline float bf2f(u16 u) {
    union { float f; unsigned v; } x; x.v = ((unsigned)u) << 16; return x.f;
}
__device__ inline u16 f2bf(float f) {   // hardware RNE cvt on gfx950
    __bf16 h = (__bf16)f;
    return *(u16*)&h;
}
// pack 8 fp32 (two int4 reg blocks) -> 8 bf16 (one int4)
__device__ inline int4 cvt8(int4 lo, int4 hi) {
    const float* fa = (const float*)&lo;
    const float* fb = (const float*)&hi;
    __attribute__((aligned(16))) u16 o[8] = {
        f2bf(fa[0]), f2bf(fa[1]), f2bf(fa[2]), f2bf(fa[3]),
        f2bf(fb[0]), f2bf(fb[1]), f2bf(fb[2]), f2bf(fb[3]) };
    return *(const int4*)o;
}

// Inline dtype probe: all threads read the SAME first 128 dwords of x.
// fp32 read as bf16 -> ~25% of low halves have |v|>=2^65. bf16 data: 0 hits.
__device__ __forceinline__ int detect_fp32(const unsigned* __restrict__ xw) {
    int cnt = 0;
#pragma unroll
    for (int i = 0; i < 128; i++) {
        unsigned w = xw[i];
        cnt += (((w >> 7)  & 0xFF) >= 0xC0);
        cnt += (((w >> 23) & 0xFF) >= 0xC0);
    }
    return cnt > 8;
}

// async global->LDS DMA, 16B per lane (m97). Dest must be uniform + lane*16.
__device__ __forceinline__ void gl_lds16(const u16* g, u16* l) {
    __builtin_amdgcn_global_load_lds(
        (const __attribute__((address_space(1))) unsigned int*)g,
        (__attribute__((address_space(3))) unsigned int*)l,
        16, 0, 0);
}

// ---------------------------------------------------------------------------
// Fused converter: ALL 7 inputs -> bf16 in one launch (8 elems/thread).
// ---------------------------------------------------------------------------
struct ConvDesc {
    const void* src[7];
    u16*        dst[7];
    int         off8[8];
};

__global__ void convert_all(ConvDesc cd)
{
    const int fl = detect_fp32((const unsigned*)cd.src[0]);
    int gid = blockIdx.x * blockDim.x + threadIdx.x;
    if (gid >= cd.off8[7]) return;
    int seg = 0;
#pragma unroll
    for (int s = 1; s < 7; s++) seg += (gid >= cd.off8[s]);
    int i = (gid - cd.off8[seg]) * 8;
    if (fl) {
        const float4* s = (const float4*)((const float*)cd.src[seg] + i);
        *(int4*)(cd.dst[seg] + i) = cvt8(*(const int4*)&s[0], *(const int4*)&s[1]);
    } else {
        *(int4*)(cd.dst[seg] + i) = *(const int4*)((const u16*)cd.src[seg] + i);
    }
}

// ---------------------------------------------------------------------------
// GEMM1 + RoPE/scatter (R12-frozen structure): 64(M)x128(N), BK=64,
// XOR-swizzled DMA, dbuf LDS (48 KB -> 3/CU, grid 768), 1 barrier/K-step.
// Q is scaled by 0.125*log2(e) so flash can use the raw v_exp_f32.
// ---------------------------------------------------------------------------
__global__ __launch_bounds__(256) void gemm_qkv_rope(
    const u16* __restrict__ A, const u16* __restrict__ W,
    const u16* __restrict__ bias,
    const u16* __restrict__ ccos, const u16* __restrict__ csin,
    u16* __restrict__ Qout, u16* __restrict__ Kout, u16* __restrict__ Vtout)
{
    __shared__ __attribute__((aligned(16))) u16 lds_a[2][64 * 64];
    __shared__ __attribute__((aligned(16))) u16 lds_b[2][128 * 64];

    const int tid  = threadIdx.x;
    const int wave = tid >> 6;
    const int lane = tid & 63;
    const int quad = lane >> 4;
    const int l16  = lane & 15;
    const int bm = blockIdx.y * 64;
    const int bn = blockIdx.x * 128;
    const int K = C_DIM;

    f32x4 acc[4][2] = {};

    int srow[4], sgc[4];
#pragma unroll
    for (int k = 0; k < 4; k++) {
        int s = tid + k * 256;
        srow[k] = s >> 3;
        sgc[k]  = (s & 7) ^ (srow[k] & 7);
    }
    const int xh = l16 & 7;

    auto stage = [&](int k0, int p) {
#pragma unroll
        for (int k = 0; k < 2; k++) {
            int s = tid + k * 256;
            gl_lds16(A + (size_t)(bm + srow[k]) * K + k0 + sgc[k] * 8, lds_a[p] + s * 8);
        }
#pragma unroll
        for (int k = 0; k < 4; k++) {
            int s = tid + k * 256;
            gl_lds16(W + (size_t)(bn + srow[k]) * K + k0 + sgc[k] * 8, lds_b[p] + s * 8);
        }
    };

    stage(0, 0);
    const int nsteps = K / 64;   // 32
    for (int kt = 0; kt < nsteps; kt++) {
        const int p = kt & 1;
        __syncthreads();   // certifies DMA(->buf p) complete; one barrier/step
        if (kt + 1 < nsteps) stage((kt + 1) * 64, p ^ 1);

        bf16x8 afr[4][2], bfr[2][2];
#pragma unroll
        for (int ks = 0; ks < 2; ks++) {
            int c = ((ks * 4 + quad) ^ xh) * 8;
#pragma unroll
            for (int i = 0; i < 4; i++)
                afr[i][ks] = *(const bf16x8*)(lds_a[p] + (i * 16 + l16) * 64 + c);
#pragma unroll
            for (int j = 0; j < 2; j++)
                bfr[j][ks] = *(const bf16x8*)(lds_b[p] + (wave * 32 + j * 16 + l16) * 64 + c);
        }
#pragma unroll
        for (int ks = 0; ks < 2; ks++)
#pragma unroll
            for (int i = 0; i < 4; i++)
#pragma unroll
                for (int j = 0; j < 2; j++)
                    acc[i][j] = __builtin_amdgcn_mfma_f32_16x16x32_bf16(afr[i][ks], bfr[j][ks], acc[i][j], 0, 0, 0);
    }

    // epilogue: bias + RoPE + scatter
#pragma unroll
    for (int j = 0; j < 2; j++) {
        const int colb = bn + wave * 32 + j * 16;      // wave-uniform
        const int col  = colb + l16;
        const int slot = (colb % 384) >> 6;            // 0..3 q, 4 k, 5 v
        const int g    = colb / 384;
        const int dbase = colb & 63;
        const int d    = dbase + l16;
        const float bv = bf2f(bias[col]);
        const bool rope = (dbase == 0) && (slot != 5);
#pragma unroll
        for (int i = 0; i < 4; i++) {
            const int trow = bm + i * 16 + quad * 4;
#pragma unroll
            for (int r = 0; r < 4; r++) {
                float v = acc[i][j][r] + bv;
                float outv = v;
                if (rope) {
                    float part = __shfl_xor(v, 8, 64);
                    float rot = (l16 < 8) ? -part : part;
                    float cc = bf2f(ccos[(trow + r) * ROPE_N + l16]);
                    float ss = bf2f(csin[(trow + r) * ROPE_N + l16]);
                    outv = v * cc + rot * ss;
                }
                const int t = trow + r;
                if (slot < 4) {
                    int hh = g * 4 + slot;
                    Qout[((size_t)hh * T_SEQ + t) * 64 + d] = f2bf(outv * QSCALE);
                } else if (slot == 4) {
                    Kout[((size_t)g * T_SEQ + t) * 64 + d] = f2bf(outv);
                } else {
                    Vtout[((size_t)g * 64 + d) * T_SEQ + t] = f2bf(outv);
                }
            }
        }
    }
}

// ---------------------------------------------------------------------------
// GEMM2 (R13-frozen): 64x64 tile, grid 1024 = 4/CU, BK=64, swizzled DMA,
// dbuf LDS (32 KB), 1 barrier/step. Output dtype via inline probe.
// ---------------------------------------------------------------------------
__global__ __launch_bounds__(256) void gemm_bt(
    const u16* __restrict__ A, const u16* __restrict__ W,
    const u16* __restrict__ bias, u16* __restrict__ Cout,
    int M, int N, int K, const unsigned* __restrict__ xprobe)
{
    __shared__ __attribute__((aligned(16))) u16 lds_a[2][64 * 64];
    __shared__ __attribute__((aligned(16))) u16 lds_b[2][64 * 64];

    const int tid  = threadIdx.x;
    const int wave = tid >> 6;
    const int lane = tid & 63;
    const int quad = lane >> 4;
    const int l16  = lane & 15;
    const int bm = blockIdx.y * 64;
    const int bn = blockIdx.x * 64;
    const int fl = detect_fp32(xprobe);

    f32x4 acc[4] = {};

    int srow[2], sgc[2];
#pragma unroll
    for (int k = 0; k < 2; k++) {
        int s = tid + k * 256;
        srow[k] = s >> 3;
        sgc[k]  = (s & 7) ^ (srow[k] & 7);
    }
    const int xh = l16 & 7;

    auto stage = [&](int k0, int p) {
#pragma unroll
        for (int k = 0; k < 2; k++) {
            int s = tid + k * 256;
            gl_lds16(A + (size_t)(bm + srow[k]) * K + k0 + sgc[k] * 8, lds_a[p] + s * 8);
            gl_lds16(W + (size_t)(bn + srow[k]) * K + k0 + sgc[k] * 8, lds_b[p] + s * 8);
        }
    };

    stage(0, 0);
    const int nsteps = K / 64;
    for (int kt = 0; kt < nsteps; kt++) {
        const int p = kt & 1;
        __syncthreads();   // certifies DMA(->buf p) complete
        if (kt + 1 < nsteps) stage((kt + 1) * 64, p ^ 1);

        bf16x8 afr[4][2], bfr[2];
#pragma unroll
        for (int ks = 0; ks < 2; ks++) {
            int c = ((ks * 4 + quad) ^ xh) * 8;
#pragma unroll
            for (int i = 0; i < 4; i++)
                afr[i][ks] = *(const bf16x8*)(lds_a[p] + (i * 16 + l16) * 64 + c);
            bfr[ks] = *(const bf16x8*)(lds_b[p] + (wave * 16 + l16) * 64 + c);
        }
#pragma unroll
        for (int ks = 0; ks < 2; ks++)
#pragma unroll
            for (int i = 0; i < 4; i++)
                acc[i] = __builtin_amdgcn_mfma_f32_16x16x32_bf16(afr[i][ks], bfr[ks], acc[i], 0, 0, 0);
    }

    const int col = bn + wave * 16 + l16;
    const float bv = bf2f(bias[col]);
#pragma unroll
    for (int i = 0; i < 4; i++) {
        int row = bm + i * 16 + quad * 4;
#pragma unroll
        for (int r = 0; r < 4; r++) {
            float v = acc[i][r] + bv;
            size_t idx = (size_t)(row + r) * N + col;
            if (fl) ((float*)Cout)[idx] = v;
            else    Cout[idx] = f2bf(v);
        }
    }
}

// ---------------------------------------------------------------------------
// Flash attention v4: same math as v3.3 (ones-MFMA row-sum, bare v_exp_f32,
// diagonal-only masking, LSP=76 P buffer) but staging goes through
// global_load_lds DMA with the GEMMs' XOR-swizzle (stride 64, measured
// 0-conflict in R11) instead of register round-trips. LDS 55.8->49.7 KB
// -> 3 blocks/CU. Grid (32,32)=1024 blocks, LONGEST-FIRST (qt = 31-bx) so
// diagonal blocks start early and short blocks backfill the tail.
// One barrier per k-tile (GEMM-style dbuf DMA loop).
// ---------------------------------------------------------------------------
__global__ __launch_bounds__(256) void flash_attn(
    const u16* __restrict__ Q, const u16* __restrict__ K,
    const u16* __restrict__ Vt, u16* __restrict__ Y)
{
    __shared__ __attribute__((aligned(16))) u16 lds_q[64 * 64];
    __shared__ __attribute__((aligned(16))) u16 lds_k[2][64 * 64];
    __shared__ __attribute__((aligned(16))) u16 lds_vt[2][64 * 64];
    __shared__ __attribute__((aligned(16))) u16 lds_p[4][16 * LSP];

    const int h  = blockIdx.y;
    const int g  = h >> 2;
    const int qt = 31 - blockIdx.x;   // longest-first
    const int q0 = qt * 64;
    const int tid  = threadIdx.x;
    const int wave = tid >> 6;
    const int lane = tid & 63;
    const int quad = lane >> 4;
    const int l16  = lane & 15;

    const u16* Qh = Q  + (size_t)h * T_SEQ * 64;
    const u16* Kg = K  + (size_t)g * T_SEQ * 64;
    const u16* Vg = Vt + (size_t)g * 64 * T_SEQ;   // [d][T]

    // staging geometry: 512 slots of 8 elems; thread covers s = tid, tid+256.
    // slot s -> row s>>3, physical chunk (s&7)^(row&7)  [R11 swizzle, 0-conflict]
    int srow[2], sgc[2];
#pragma unroll
    for (int k = 0; k < 2; k++) {
        int s = tid + k * 256;
        srow[k] = s >> 3;
        sgc[k]  = (s & 7) ^ (srow[k] & 7);
    }
    const int xh = l16 & 7;

    bf16x8 vones;
#pragma unroll
    for (int i = 0; i < 8; i++) vones[i] = (__bf16)1.0f;

    auto stage = [&](int k0, int p) {
#pragma unroll
        for (int k = 0; k < 2; k++) {
            int s = tid + k * 256;
            gl_lds16(Kg + (size_t)(k0 + srow[k]) * 64 + sgc[k] * 8, lds_k[p] + s * 8);
            gl_lds16(Vg + (size_t)srow[k] * T_SEQ + k0 + sgc[k] * 8, lds_vt[p] + s * 8);
        }
    };

    // stage Q (once) + first K/Vt tile via DMA
#pragma unroll
    for (int k = 0; k < 2; k++) {
        int s = tid + k * 256;
        gl_lds16(Qh + (size_t)(q0 + srow[k]) * 64 + sgc[k] * 8, lds_q + s * 8);
    }
    stage(0, 0);

    f32x4 o_acc[4] = {};
    f32x4 acc_l = {};   // row-sum accumulator (ones-MFMA)
    bf16x8 a_q[2];
    bool q_loaded = false;

    for (int kt = 0; kt <= qt; kt++) {
        const int p = kt & 1;
        __syncthreads();   // drains DMA for buf p (and Q on the first iter)
        if (kt < qt) stage((kt + 1) * 64, p ^ 1);

        if (!q_loaded) {   // first iteration: pull Q fragments (swizzled)
#pragma unroll
            for (int ks = 0; ks < 2; ks++)
                a_q[ks] = *(const bf16x8*)(lds_q + (wave * 16 + l16) * 64 + (((ks * 4 + quad) ^ xh) * 8));
            q_loaded = true;
        }

        f32x4 sc[4] = {};
#pragma unroll
        for (int ks = 0; ks < 2; ks++) {
            int c = ((ks * 4 + quad) ^ xh) * 8;
#pragma unroll
            for (int t = 0; t < 4; t++) {
                bf16x8 bk = *(const bf16x8*)(lds_k[p] + (t * 16 + l16) * 64 + c);
                sc[t] = __builtin_amdgcn_mfma_f32_16x16x32_bf16(a_q[ks], bk, sc[t], 0, 0, 0);
            }
        }

        if (kt == qt) {   // only the diagonal tile needs masking
            const int row_g = q0 + wave * 16 + quad * 4;
            const int k0 = kt * 64;
#pragma unroll
            for (int t = 0; t < 4; t++) {
                int col_g = k0 + t * 16 + l16;
#pragma unroll
                for (int r = 0; r < 4; r++)
                    if (col_g > row_g + r) sc[t][r] = NEG_BIG;
            }
        }

#pragma unroll
        for (int t = 0; t < 4; t++) {
            int colo = t * 16 + l16;
#pragma unroll
            for (int r = 0; r < 4; r++) {
                float pv = __builtin_amdgcn_exp2f(sc[t][r]);  // bare v_exp_f32
                lds_p[wave][(quad * 4 + r) * LSP + colo] = f2bf(pv);
            }
        }
        // no barrier: lds_p is wave-private (same-wave DS ops in order)

#pragma unroll
        for (int ks = 0; ks < 2; ks++) {
            int c = ((ks * 4 + quad) ^ xh) * 8;
            bf16x8 apf = *(const bf16x8*)(lds_p[wave] + l16 * LSP + ks * 32 + quad * 8);
#pragma unroll
            for (int t = 0; t < 4; t++) {
                bf16x8 bvf = *(const bf16x8*)(lds_vt[p] + (t * 16 + l16) * 64 + c);
                o_acc[t] = __builtin_amdgcn_mfma_f32_16x16x32_bf16(apf, bvf, o_acc[t], 0, 0, 0);
            }
            acc_l = __builtin_amdgcn_mfma_f32_16x16x32_bf16(apf, vones, acc_l, 0, 0, 0);
        }
    }

    // acc_l[r] == row sum, already replicated across the 16 lanes
#pragma unroll
    for (int t = 0; t < 4; t++)
#pragma unroll
        for (int r = 0; r < 4; r++) {
            int row = q0 + wave * 16 + quad * 4 + r;
            int d   = t * 16 + l16;
            Y[(size_t)row * (N_HEAD * HEAD_SIZE) + h * 64 + d] = f2bf(o_acc[t][r] / acc_l[r]);
        }
}

// ---------------------------------------------------------------------------
extern "C" void kernel_launch(void* const* d_in, const int* in_sizes, int n_in,
                              void* d_out, int out_size, void* d_ws, size_t ws_size,
                              hipStream_t stream)
{
    u16* base = (u16*)d_ws;

    u16* cx   = base;                                      // 2048*2048
    u16* cWa  = cx  + (size_t)T_SEQ * C_DIM;               // 3072*2048
    u16* cba  = cWa + (size_t)QKV_DIM * C_DIM;             // 3072
    u16* cWp  = cba + QKV_DIM;                             // 2048*2048
    u16* cbp  = cWp + (size_t)C_DIM * C_DIM;               // 2048
    u16* ccos = cbp + C_DIM;                               // 2048*16
    u16* csin = ccos + (size_t)T_SEQ * ROPE_N;             // 2048*16
    u16* Qb   = csin + (size_t)T_SEQ * ROPE_N;             // 32*2048*64
    u16* Kb   = Qb + (size_t)N_HEAD * T_SEQ * HEAD_SIZE;   // 8*2048*64
    u16* Vtb  = Kb + (size_t)N_GROUPS * T_SEQ * HEAD_SIZE; // 8*64*2048 (transposed)
    u16* Yb   = Vtb + (size_t)N_GROUPS * T_SEQ * HEAD_SIZE;// 2048*2048

    dim3 blk(256);

    ConvDesc cd;
    const int sizes[7] = { T_SEQ * C_DIM, T_SEQ * ROPE_N, T_SEQ * ROPE_N,
                           QKV_DIM * C_DIM, QKV_DIM, C_DIM * C_DIM, C_DIM };
    u16* dsts[7] = { cx, ccos, csin, cWa, cba, cWp, cbp };
    int acc8 = 0;
    for (int i = 0; i < 7; i++) {
        cd.src[i] = d_in[i];
        cd.dst[i] = dsts[i];
        cd.off8[i] = acc8;
        acc8 += sizes[i] / 8;
    }
    cd.off8[7] = acc8;
    convert_all<<<dim3((acc8 + 255) / 256), blk, 0, stream>>>(cd);

    gemm_qkv_rope<<<dim3(QKV_DIM / 128, T_SEQ / 64), blk, 0, stream>>>(
        cx, cWa, cba, ccos, csin, Qb, Kb, Vtb);
    flash_attn<<<dim3(T_SEQ / 64, N_HEAD), blk, 0, stream>>>(Qb, Kb, Vtb, Yb);
    gemm_bt<<<dim3(C_DIM / 64, T_SEQ / 64), blk, 0, stream>>>(
        Yb, cWp, cbp, (u16*)d_out, T_SEQ, C_DIM, N_HEAD * HEAD_SIZE,
        (const unsigned*)d_in[0]);
}

// Round 17
// 247.033 us; speedup vs baseline: 1.1395x; 1.1395x over previous
//
#include <hip/hip_runtime.h>
#include <hip/hip_bf16.h>

using u16 = unsigned short;
typedef float f32x4 __attribute__((ext_vector_type(4)));
typedef __bf16 bf16x8 __attribute__((ext_vector_type(8)));

#define T_SEQ 2048
#define C_DIM 2048
#define QKV_DIM 3072
#define N_HEAD 32
#define N_GROUPS 8
#define HEAD_SIZE 64
#define ROPE_N 16
#define NEG_BIG (-1e30f)
#define LSP 76    // lds_p row stride: 38 dwords/row -> quad offsets {0,24,16,8}, conflict-free
#define QSCALE 0.18033688011112043f   // 0.125 * log2(e): folds softmax's exp->exp2 conversion into Q

__device__ inline float bf2f(u16 u) {
    union { float f; unsigned v; } x; x.v = ((unsigned)u) << 16; return x.f;
}
__device__ inline u16 f2bf(float f) {   // hardware RNE cvt on gfx950
    __bf16 h = (__bf16)f;
    return *(u16*)&h;
}
// pack 8 fp32 (two int4 reg blocks) -> 8 bf16 (one int4)
__device__ inline int4 cvt8(int4 lo, int4 hi) {
    const float* fa = (const float*)&lo;
    const float* fb = (const float*)&hi;
    __attribute__((aligned(16))) u16 o[8] = {
        f2bf(fa[0]), f2bf(fa[1]), f2bf(fa[2]), f2bf(fa[3]),
        f2bf(fb[0]), f2bf(fb[1]), f2bf(fb[2]), f2bf(fb[3]) };
    return *(const int4*)o;
}

// Inline dtype probe: all threads read the SAME first 128 dwords of x.
// fp32 read as bf16 -> ~25% of low halves have |v|>=2^65. bf16 data: 0 hits.
__device__ __forceinline__ int detect_fp32(const unsigned* __restrict__ xw) {
    int cnt = 0;
#pragma unroll
    for (int i = 0; i < 128; i++) {
        unsigned w = xw[i];
        cnt += (((w >> 7)  & 0xFF) >= 0xC0);
        cnt += (((w >> 23) & 0xFF) >= 0xC0);
    }
    return cnt > 8;
}

// async global->LDS DMA, 16B per lane (m97). Dest must be uniform + lane*16.
__device__ __forceinline__ void gl_lds16(const u16* g, u16* l) {
    __builtin_amdgcn_global_load_lds(
        (const __attribute__((address_space(1))) unsigned int*)g,
        (__attribute__((address_space(3))) unsigned int*)l,
        16, 0, 0);
}

// ---------------------------------------------------------------------------
// Fused converter: ALL 7 inputs -> bf16 in one launch (8 elems/thread).
// ---------------------------------------------------------------------------
struct ConvDesc {
    const void* src[7];
    u16*        dst[7];
    int         off8[8];
};

__global__ void convert_all(ConvDesc cd)
{
    const int fl = detect_fp32((const unsigned*)cd.src[0]);
    int gid = blockIdx.x * blockDim.x + threadIdx.x;
    if (gid >= cd.off8[7]) return;
    int seg = 0;
#pragma unroll
    for (int s = 1; s < 7; s++) seg += (gid >= cd.off8[s]);
    int i = (gid - cd.off8[seg]) * 8;
    if (fl) {
        const float4* s = (const float4*)((const float*)cd.src[seg] + i);
        *(int4*)(cd.dst[seg] + i) = cvt8(*(const int4*)&s[0], *(const int4*)&s[1]);
    } else {
        *(int4*)(cd.dst[seg] + i) = *(const int4*)((const u16*)cd.src[seg] + i);
    }
}

// ---------------------------------------------------------------------------
// GEMM1 + RoPE/scatter (R12-frozen structure): 64(M)x128(N), BK=64,
// XOR-swizzled DMA, dbuf LDS (48 KB -> 3/CU, grid 768), 1 barrier/K-step.
// Q is scaled by 0.125*log2(e) so flash can use the raw v_exp_f32.
// ---------------------------------------------------------------------------
__global__ __launch_bounds__(256) void gemm_qkv_rope(
    const u16* __restrict__ A, const u16* __restrict__ W,
    const u16* __restrict__ bias,
    const u16* __restrict__ ccos, const u16* __restrict__ csin,
    u16* __restrict__ Qout, u16* __restrict__ Kout, u16* __restrict__ Vtout)
{
    __shared__ __attribute__((aligned(16))) u16 lds_a[2][64 * 64];
    __shared__ __attribute__((aligned(16))) u16 lds_b[2][128 * 64];

    const int tid  = threadIdx.x;
    const int wave = tid >> 6;
    const int lane = tid & 63;
    const int quad = lane >> 4;
    const int l16  = lane & 15;
    const int bm = blockIdx.y * 64;
    const int bn = blockIdx.x * 128;
    const int K = C_DIM;

    f32x4 acc[4][2] = {};

    int srow[4], sgc[4];
#pragma unroll
    for (int k = 0; k < 4; k++) {
        int s = tid + k * 256;
        srow[k] = s >> 3;
        sgc[k]  = (s & 7) ^ (srow[k] & 7);
    }
    const int xh = l16 & 7;

    auto stage = [&](int k0, int p) {
#pragma unroll
        for (int k = 0; k < 2; k++) {
            int s = tid + k * 256;
            gl_lds16(A + (size_t)(bm + srow[k]) * K + k0 + sgc[k] * 8, lds_a[p] + s * 8);
        }
#pragma unroll
        for (int k = 0; k < 4; k++) {
            int s = tid + k * 256;
            gl_lds16(W + (size_t)(bn + srow[k]) * K + k0 + sgc[k] * 8, lds_b[p] + s * 8);
        }
    };

    stage(0, 0);
    const int nsteps = K / 64;   // 32
    for (int kt = 0; kt < nsteps; kt++) {
        const int p = kt & 1;
        __syncthreads();   // certifies DMA(->buf p) complete; one barrier/step
        if (kt + 1 < nsteps) stage((kt + 1) * 64, p ^ 1);

        bf16x8 afr[4][2], bfr[2][2];
#pragma unroll
        for (int ks = 0; ks < 2; ks++) {
            int c = ((ks * 4 + quad) ^ xh) * 8;
#pragma unroll
            for (int i = 0; i < 4; i++)
                afr[i][ks] = *(const bf16x8*)(lds_a[p] + (i * 16 + l16) * 64 + c);
#pragma unroll
            for (int j = 0; j < 2; j++)
                bfr[j][ks] = *(const bf16x8*)(lds_b[p] + (wave * 32 + j * 16 + l16) * 64 + c);
        }
#pragma unroll
        for (int ks = 0; ks < 2; ks++)
#pragma unroll
            for (int i = 0; i < 4; i++)
#pragma unroll
                for (int j = 0; j < 2; j++)
                    acc[i][j] = __builtin_amdgcn_mfma_f32_16x16x32_bf16(afr[i][ks], bfr[j][ks], acc[i][j], 0, 0, 0);
    }

    // epilogue: bias + RoPE + scatter
#pragma unroll
    for (int j = 0; j < 2; j++) {
        const int colb = bn + wave * 32 + j * 16;      // wave-uniform
        const int col  = colb + l16;
        const int slot = (colb % 384) >> 6;            // 0..3 q, 4 k, 5 v
        const int g    = colb / 384;
        const int dbase = colb & 63;
        const int d    = dbase + l16;
        const float bv = bf2f(bias[col]);
        const bool rope = (dbase == 0) && (slot != 5);
#pragma unroll
        for (int i = 0; i < 4; i++) {
            const int trow = bm + i * 16 + quad * 4;
#pragma unroll
            for (int r = 0; r < 4; r++) {
                float v = acc[i][j][r] + bv;
                float outv = v;
                if (rope) {
                    float part = __shfl_xor(v, 8, 64);
                    float rot = (l16 < 8) ? -part : part;
                    float cc = bf2f(ccos[(trow + r) * ROPE_N + l16]);
                    float ss = bf2f(csin[(trow + r) * ROPE_N + l16]);
                    outv = v * cc + rot * ss;
                }
                const int t = trow + r;
                if (slot < 4) {
                    int hh = g * 4 + slot;
                    Qout[((size_t)hh * T_SEQ + t) * 64 + d] = f2bf(outv * QSCALE);
                } else if (slot == 4) {
                    Kout[((size_t)g * T_SEQ + t) * 64 + d] = f2bf(outv);
                } else {
                    Vtout[((size_t)g * 64 + d) * T_SEQ + t] = f2bf(outv);
                }
            }
        }
    }
}

// ---------------------------------------------------------------------------
// GEMM2 (R13-frozen): 64x64 tile, grid 1024 = 4/CU, BK=64, swizzled DMA,
// dbuf LDS (32 KB), 1 barrier/step. Output dtype via inline probe.
// ---------------------------------------------------------------------------
__global__ __launch_bounds__(256) void gemm_bt(
    const u16* __restrict__ A, const u16* __restrict__ W,
    const u16* __restrict__ bias, u16* __restrict__ Cout,
    int M, int N, int K, const unsigned* __restrict__ xprobe)
{
    __shared__ __attribute__((aligned(16))) u16 lds_a[2][64 * 64];
    __shared__ __attribute__((aligned(16))) u16 lds_b[2][64 * 64];

    const int tid  = threadIdx.x;
    const int wave = tid >> 6;
    const int lane = tid & 63;
    const int quad = lane >> 4;
    const int l16  = lane & 15;
    const int bm = blockIdx.y * 64;
    const int bn = blockIdx.x * 64;
    const int fl = detect_fp32(xprobe);

    f32x4 acc[4] = {};

    int srow[2], sgc[2];
#pragma unroll
    for (int k = 0; k < 2; k++) {
        int s = tid + k * 256;
        srow[k] = s >> 3;
        sgc[k]  = (s & 7) ^ (srow[k] & 7);
    }
    const int xh = l16 & 7;

    auto stage = [&](int k0, int p) {
#pragma unroll
        for (int k = 0; k < 2; k++) {
            int s = tid + k * 256;
            gl_lds16(A + (size_t)(bm + srow[k]) * K + k0 + sgc[k] * 8, lds_a[p] + s * 8);
            gl_lds16(W + (size_t)(bn + srow[k]) * K + k0 + sgc[k] * 8, lds_b[p] + s * 8);
        }
    };

    stage(0, 0);
    const int nsteps = K / 64;
    for (int kt = 0; kt < nsteps; kt++) {
        const int p = kt & 1;
        __syncthreads();   // certifies DMA(->buf p) complete
        if (kt + 1 < nsteps) stage((kt + 1) * 64, p ^ 1);

        bf16x8 afr[4][2], bfr[2];
#pragma unroll
        for (int ks = 0; ks < 2; ks++) {
            int c = ((ks * 4 + quad) ^ xh) * 8;
#pragma unroll
            for (int i = 0; i < 4; i++)
                afr[i][ks] = *(const bf16x8*)(lds_a[p] + (i * 16 + l16) * 64 + c);
            bfr[ks] = *(const bf16x8*)(lds_b[p] + (wave * 16 + l16) * 64 + c);
        }
#pragma unroll
        for (int ks = 0; ks < 2; ks++)
#pragma unroll
            for (int i = 0; i < 4; i++)
                acc[i] = __builtin_amdgcn_mfma_f32_16x16x32_bf16(afr[i][ks], bfr[ks], acc[i], 0, 0, 0);
    }

    const int col = bn + wave * 16 + l16;
    const float bv = bf2f(bias[col]);
#pragma unroll
    for (int i = 0; i < 4; i++) {
        int row = bm + i * 16 + quad * 4;
#pragma unroll
        for (int r = 0; r < 4; r++) {
            float v = acc[i][r] + bv;
            size_t idx = (size_t)(row + r) * N + col;
            if (fl) ((float*)Cout)[idx] = v;
            else    Cout[idx] = f2bf(v);
        }
    }
}

// ---------------------------------------------------------------------------
// Flash attention v3.4 = R15's proven v3.3 (64-row Q tiles, paired
// {bx,31-bx} 512-block grid, REGISTER prefetch of K/Vt — each wave absorbs
// its own global-load latency before the barrier, which the R16 DMA variant
// lost — 1 barrier/k-tile, ones-MFMA row-sum, bare v_exp_f32, LSP=76)
// with ONE change: K/Vt/Q staged at stride 64 + XOR swizzle (correctness
// verified in R16, 0-conflict in R11) instead of padded stride 72. Manual
// b128 writes land at slot*16B (lane-contiguous, conflict-free); fragment
// reads use physical chunk = (global chunk) ^ (row & 7).
// ---------------------------------------------------------------------------
__global__ __launch_bounds__(256) void flash_attn(
    const u16* __restrict__ Q, const u16* __restrict__ K,
    const u16* __restrict__ Vt, u16* __restrict__ Y)
{
    __shared__ __attribute__((aligned(16))) u16 lds_q[64 * 64];
    __shared__ __attribute__((aligned(16))) u16 lds_k[2][64 * 64];
    __shared__ __attribute__((aligned(16))) u16 lds_vt[2][64 * 64];
    __shared__ __attribute__((aligned(16))) u16 lds_p[4][16 * LSP];

    const int h  = blockIdx.y;
    const int g  = h >> 2;
    const int tid  = threadIdx.x;
    const int wave = tid >> 6;
    const int lane = tid & 63;
    const int quad = lane >> 4;
    const int l16  = lane & 15;
    const int NQT = T_SEQ / 64;

    const u16* Qh = Q  + (size_t)h * T_SEQ * 64;
    const u16* Kg = K  + (size_t)g * T_SEQ * 64;
    const u16* Vg = Vt + (size_t)g * 64 * T_SEQ;   // [d][T]

    // staging: slot s in {tid, tid+256} -> row s>>3 (rows r, r+32 share
    // (row&7)), physical chunk s&7, global chunk (s&7)^(row&7)
    const int srow = tid >> 3;
    const int sgc  = (tid & 7) ^ (srow & 7);
    const int xh   = l16 & 7;

    bf16x8 vones;
#pragma unroll
    for (int i = 0; i < 8; i++) vones[i] = (__bf16)1.0f;

    int4 kr0, kr1, vr0, vr1;
    auto load_tile = [&](int k0) {
        kr0 = *(const int4*)(Kg + (size_t)(k0 + srow) * 64 + sgc * 8);
        kr1 = *(const int4*)(Kg + (size_t)(k0 + srow + 32) * 64 + sgc * 8);
        vr0 = *(const int4*)(Vg + (size_t)srow * T_SEQ + k0 + sgc * 8);
        vr1 = *(const int4*)(Vg + (size_t)(srow + 32) * T_SEQ + k0 + sgc * 8);
    };

    for (int pass = 0; pass < 2; pass++) {
        const int qt = pass ? (NQT - 1 - blockIdx.x) : blockIdx.x;
        const int q0 = qt * 64;

        __syncthreads();
        // stage Q tile (swizzled, manual writes at slot*16B)
#pragma unroll
        for (int k = 0; k < 2; k++) {
            int s = tid + k * 256;
            int row = srow + k * 32;
            *(int4*)(lds_q + s * 8) =
                *(const int4*)(Qh + (size_t)(q0 + row) * 64 + sgc * 8);
        }
        __syncthreads();

        bf16x8 a_q[2];
#pragma unroll
        for (int ks = 0; ks < 2; ks++)
            a_q[ks] = *(const bf16x8*)(lds_q + (wave * 16 + l16) * 64 + (((ks * 4 + quad) ^ xh) * 8));

        f32x4 o_acc[4] = {};
        f32x4 acc_l = {};   // row-sum accumulator (ones-MFMA)

        load_tile(0);

        for (int kt = 0; kt <= qt; kt++) {
            const int p = kt & 1;
            *(int4*)(lds_k[p]  + tid * 8)         = kr0;
            *(int4*)(lds_k[p]  + (tid + 256) * 8) = kr1;
            *(int4*)(lds_vt[p] + tid * 8)         = vr0;
            *(int4*)(lds_vt[p] + (tid + 256) * 8) = vr1;
            __syncthreads();   // the ONLY barrier in the k-loop
            if (kt < qt) load_tile((kt + 1) * 64);

            f32x4 sc[4] = {};
#pragma unroll
            for (int ks = 0; ks < 2; ks++) {
                int c = ((ks * 4 + quad) ^ xh) * 8;
#pragma unroll
                for (int t = 0; t < 4; t++) {
                    bf16x8 bk = *(const bf16x8*)(lds_k[p] + (t * 16 + l16) * 64 + c);
                    sc[t] = __builtin_amdgcn_mfma_f32_16x16x32_bf16(a_q[ks], bk, sc[t], 0, 0, 0);
                }
            }

            if (kt == qt) {   // only the diagonal tile needs masking
                const int row_g = q0 + wave * 16 + quad * 4;
                const int k0 = kt * 64;
#pragma unroll
                for (int t = 0; t < 4; t++) {
                    int col_g = k0 + t * 16 + l16;
#pragma unroll
                    for (int r = 0; r < 4; r++)
                        if (col_g > row_g + r) sc[t][r] = NEG_BIG;
                }
            }

#pragma unroll
            for (int t = 0; t < 4; t++) {
                int colo = t * 16 + l16;
#pragma unroll
                for (int r = 0; r < 4; r++) {
                    float pv = __builtin_amdgcn_exp2f(sc[t][r]);  // bare v_exp_f32
                    lds_p[wave][(quad * 4 + r) * LSP + colo] = f2bf(pv);
                }
            }
            // no barrier: lds_p is wave-private (same-wave DS ops in order)

#pragma unroll
            for (int ks = 0; ks < 2; ks++) {
                int c = ((ks * 4 + quad) ^ xh) * 8;
                bf16x8 apf = *(const bf16x8*)(lds_p[wave] + l16 * LSP + ks * 32 + quad * 8);
#pragma unroll
                for (int t = 0; t < 4; t++) {
                    bf16x8 bvf = *(const bf16x8*)(lds_vt[p] + (t * 16 + l16) * 64 + c);
                    o_acc[t] = __builtin_amdgcn_mfma_f32_16x16x32_bf16(apf, bvf, o_acc[t], 0, 0, 0);
                }
                acc_l = __builtin_amdgcn_mfma_f32_16x16x32_bf16(apf, vones, acc_l, 0, 0, 0);
            }
        }

        // acc_l[r] == row sum, already replicated across the 16 lanes
#pragma unroll
        for (int t = 0; t < 4; t++)
#pragma unroll
            for (int r = 0; r < 4; r++) {
                int row = q0 + wave * 16 + quad * 4 + r;
                int d   = t * 16 + l16;
                Y[(size_t)row * (N_HEAD * HEAD_SIZE) + h * 64 + d] = f2bf(o_acc[t][r] / acc_l[r]);
            }
    }
}

// ---------------------------------------------------------------------------
extern "C" void kernel_launch(void* const* d_in, const int* in_sizes, int n_in,
                              void* d_out, int out_size, void* d_ws, size_t ws_size,
                              hipStream_t stream)
{
    u16* base = (u16*)d_ws;

    u16* cx   = base;                                      // 2048*2048
    u16* cWa  = cx  + (size_t)T_SEQ * C_DIM;               // 3072*2048
    u16* cba  = cWa + (size_t)QKV_DIM * C_DIM;             // 3072
    u16* cWp  = cba + QKV_DIM;                             // 2048*2048
    u16* cbp  = cWp + (size_t)C_DIM * C_DIM;               // 2048
    u16* ccos = cbp + C_DIM;                               // 2048*16
    u16* csin = ccos + (size_t)T_SEQ * ROPE_N;             // 2048*16
    u16* Qb   = csin + (size_t)T_SEQ * ROPE_N;             // 32*2048*64
    u16* Kb   = Qb + (size_t)N_HEAD * T_SEQ * HEAD_SIZE;   // 8*2048*64
    u16* Vtb  = Kb + (size_t)N_GROUPS * T_SEQ * HEAD_SIZE; // 8*64*2048 (transposed)
    u16* Yb   = Vtb + (size_t)N_GROUPS * T_SEQ * HEAD_SIZE;// 2048*2048

    dim3 blk(256);

    ConvDesc cd;
    const int sizes[7] = { T_SEQ * C_DIM, T_SEQ * ROPE_N, T_SEQ * ROPE_N,
                           QKV_DIM * C_DIM, QKV_DIM, C_DIM * C_DIM, C_DIM };
    u16* dsts[7] = { cx, ccos, csin, cWa, cba, cWp, cbp };
    int acc8 = 0;
    for (int i = 0; i < 7; i++) {
        cd.src[i] = d_in[i];
        cd.dst[i] = dsts[i];
        cd.off8[i] = acc8;
        acc8 += sizes[i] / 8;
    }
    cd.off8[7] = acc8;
    convert_all<<<dim3((acc8 + 255) / 256), blk, 0, stream>>>(cd);

    gemm_qkv_rope<<<dim3(QKV_DIM / 128, T_SEQ / 64), blk, 0, stream>>>(
        cx, cWa, cba, ccos, csin, Qb, Kb, Vtb);
    flash_attn<<<dim3(T_SEQ / 128, N_HEAD), blk, 0, stream>>>(Qb, Kb, Vtb, Yb);
    gemm_bt<<<dim3(C_DIM / 64, T_SEQ / 64), blk, 0, stream>>>(
        Yb, cWp, cbp, (u16*)d_out, T_SEQ, C_DIM, N_HEAD * HEAD_SIZE,
        (const unsigned*)d_in[0]);
}